// Round 8
// baseline (2962.804 us; speedup 1.0000x reference)
//
#include <hip/hip_runtime.h>
#include <cstddef>
#include <cstdint>

// DynamicAutoencoder — Round 8: 256x256-tile 8-wave GEMM (BK=64) with
// both-sides LDS swizzle (T2), phase-split MFMA schedule + setprio (T5),
// XCD-chunked block swizzle (T1), double-buffered staging w/ 1 barrier/K-tile.
// enc3 (N=128) + koopman MLP stay on the proven 128^2 kernel.
// Runtime ws_size branch: un-chunked M=65536 if ws >= 450MB else 4x16384.

#define KDT 0.01f

typedef _Float16 f16;
typedef f16 f16x8 __attribute__((ext_vector_type(8)));
typedef f16 f16x4 __attribute__((ext_vector_type(4)));
typedef float f32x4 __attribute__((ext_vector_type(4)));

typedef __attribute__((address_space(1))) const unsigned int gu32;
typedef __attribute__((address_space(3))) unsigned int lu32;

__device__ __forceinline__ void gl_lds16(const void* g, void* l) {
    __builtin_amdgcn_global_load_lds((gu32*)g, (lu32*)l, 16, 0, 0);
}

__device__ __forceinline__ float fast_tanh(float x) {
    x = fminf(fmaxf(x, -15.f), 15.f);
    const float e = __expf(2.f * x);
    return (e - 1.f) / (e + 1.f);
}

// partial-sum slots (doubles): lin [0,4096) | rec [4096,6144) | pred [6144,8192)
#define PB_LIN 0
#define PB_REC 4096
#define PB_PRED 6144
#define PB_TOTAL 8192

// ===========================================================================
// 256x256 GEMM, 512 threads = 8 waves (2Mx4N), BK=64, mfma 16x16x32 f16.
// A: [M][K] f16, Wt: [N][K] f16. M%256==0, N%256==0, K%64==0, (K/64) even.
// LDS 128KB: As[2][256][64], Bs[2][256][64], both-sides st-swizzled.
// MODE 0: C = act(A@Wt^T + b). MODE 2: dec3 fused recon/pred loss vs window.
// ===========================================================================

// stage one 256x64 f16 panel: linear LDS dest (base+16*lane), source column
// pre-swizzled so reads at slot (c16 ^ (row&7)) see column c16.
__device__ __forceinline__ void stage256(const f16* __restrict__ g, char* ldsDst,
                                         int t, int K, int kk)
{
#pragma unroll
    for (int r = 0; r < 4; ++r) {
        const int row = r * 64 + (t >> 3);
        const int sc = ((t & 7) ^ (row & 7)) * 8;
        gl_lds16(g + (size_t)row * K + kk + sc, ldsDst + row * 128 + (t & 7) * 16);
    }
}

template <int MH, int NH>
__device__ __forceinline__ void phase_mfma(f32x4 (&acc)[8][4], const char* sA, const char* sB,
                                           int wm, int wn, int lm, int lk)
{
    f16x8 af[4][2], bf[2][2];
#pragma unroll
    for (int i = 0; i < 4; ++i)
#pragma unroll
        for (int ks = 0; ks < 2; ++ks) {
            const int row = wm * 128 + (MH * 4 + i) * 16 + lm;
            const int slot = (ks * 4 + lk) ^ (lm & 7);
            af[i][ks] = *(const f16x8*)(sA + row * 128 + slot * 16);
        }
#pragma unroll
    for (int j = 0; j < 2; ++j)
#pragma unroll
        for (int ks = 0; ks < 2; ++ks) {
            const int row = wn * 64 + (NH * 2 + j) * 16 + lm;
            const int slot = (ks * 4 + lk) ^ (lm & 7);
            bf[j][ks] = *(const f16x8*)(sB + row * 128 + slot * 16);
        }
    __builtin_amdgcn_s_setprio(1);
#pragma unroll
    for (int i = 0; i < 4; ++i)
#pragma unroll
        for (int j = 0; j < 2; ++j)
#pragma unroll
            for (int ks = 0; ks < 2; ++ks)
                acc[MH * 4 + i][NH * 2 + j] = __builtin_amdgcn_mfma_f32_16x16x32_f16(
                    af[i][ks], bf[j][ks], acc[MH * 4 + i][NH * 2 + j], 0, 0, 0);
    __builtin_amdgcn_s_setprio(0);
}

template <bool PREF>
__device__ __forceinline__ void run_tile(f32x4 (&acc)[8][4], char* sbase, int buf,
                                         const f16* __restrict__ Ab, const f16* __restrict__ Bb,
                                         int t, int K, int kkNext, int wm, int wn, int lm, int lk)
{
    const char* sA = sbase + buf * 32768;
    const char* sB = sbase + 65536 + buf * 32768;
    char* dA = sbase + (buf ^ 1) * 32768;
    char* dB = sbase + 65536 + (buf ^ 1) * 32768;
    phase_mfma<0, 0>(acc, sA, sB, wm, wn, lm, lk);
    if (PREF) stage256(Ab, dA, t, K, kkNext);
    phase_mfma<0, 1>(acc, sA, sB, wm, wn, lm, lk);
    if (PREF) stage256(Bb, dB, t, K, kkNext);
    phase_mfma<1, 0>(acc, sA, sB, wm, wn, lm, lk);
    phase_mfma<1, 1>(acc, sA, sB, wm, wn, lm, lk);
}

template <int MODE, bool TANH, bool OUTF16>
__global__ __launch_bounds__(512, 2) void k_gemm256(const f16* __restrict__ A,
                                                    const f16* __restrict__ Wt,
                                                    const float* __restrict__ bias,
                                                    void* __restrict__ Cv,
                                                    int M, int N, int K,
                                                    const float* __restrict__ win,
                                                    int g0,
                                                    double* __restrict__ p0,
                                                    double* __restrict__ p1)
{
    __shared__ __align__(16) f16 lds[65536];   // 128 KB
    char* sbase = (char*)lds;

    const int t  = threadIdx.x;
    const int l  = t & 63;
    const int wid = t >> 6;
    const int wm = wid >> 2, wn = wid & 3;
    const int lm = l & 15, lk = l >> 4;

    // T1: XCD-chunked swizzle (nwg % 8 == 0 for all launched shapes)
    const int gx = gridDim.x;
    const int nwg = gx * gridDim.y;
    const int orig = blockIdx.y * gx + blockIdx.x;
    const int cpx = nwg >> 3;
    const int tile = (orig & 7) * cpx + (orig >> 3);
    const int bm = tile / gx;
    const int bn = tile % gx;

    const f16* Ab = A  + (size_t)bm * 256 * K;
    const f16* Bb = Wt + (size_t)bn * 256 * K;
    const int nt = K >> 6;             // even for all shapes used (2,8,16)

    f32x4 acc[8][4] = {};

    stage256(Ab, sbase, t, K, 0);
    stage256(Bb, sbase + 65536, t, K, 0);
    __syncthreads();

    for (int kt = 0; kt < nt; kt += 2) {
        run_tile<true>(acc, sbase, 0, Ab, Bb, t, K, (kt + 1) << 6, wm, wn, lm, lk);
        __syncthreads();
        if (kt + 2 < nt) {
            run_tile<true>(acc, sbase, 1, Ab, Bb, t, K, (kt + 2) << 6, wm, wn, lm, lk);
            __syncthreads();
        } else {
            run_tile<false>(acc, sbase, 1, Ab, Bb, t, K, 0, wm, wn, lm, lk);
        }
    }

    const int row0g = bm * 256 + wm * 128;
    const int col0g = bn * 256 + wn * 64;

    if (MODE == 0) {
#pragma unroll
        for (int n = 0; n < 4; ++n) {
            const int col = col0g + n * 16 + lm;
            const float bv = bias[col];
#pragma unroll
            for (int m = 0; m < 8; ++m)
#pragma unroll
                for (int q = 0; q < 4; ++q) {
                    const int row = row0g + m * 16 + lk * 4 + q;
                    float v = acc[m][n][q] + bv;
                    if (TANH) v = fast_tanh(v);
                    if (OUTF16) ((f16*)Cv)[(size_t)row * N + col] = (f16)v;
                    else        ((float*)Cv)[(size_t)row * N + col] = v;
                }
        }
    } else {  // MODE 2: loss vs window
        double s0 = 0.0, s1 = 0.0;
        float bv[4];
#pragma unroll
        for (int n = 0; n < 4; ++n) bv[n] = bias[col0g + n * 16 + lm];
#pragma unroll
        for (int m = 0; m < 8; ++m)
#pragma unroll
            for (int q = 0; q < 4; ++q) {
                const int rl = row0g + m * 16 + lk * 4 + q;
                const int g  = g0 + rl;
                const int tt = g & 127;
#pragma unroll
                for (int n = 0; n < 4; ++n) {
                    const int col = col0g + n * 16 + lm;
                    const float v = acc[m][n][q] + bv[n];
                    const float d = v - win[(size_t)g * 512 + col];
                    if (tt == 0) s0 += (double)d * d;
                    else         s1 += (double)d * d;
                }
            }
        __syncthreads();                       // all LDS reads done; reuse as reduce buf
        double* dsm = (double*)lds;
        const int slot = (g0 / 256 + bm) * gx + bn;   // global tile slot, chunk-invariant
        dsm[t] = s0;
        __syncthreads();
        for (int o = 256; o > 0; o >>= 1) {
            if (t < o) dsm[t] += dsm[t + o];
            __syncthreads();
        }
        if (t == 0) p0[slot] = dsm[0];
        __syncthreads();
        dsm[t] = s1;
        __syncthreads();
        for (int o = 256; o > 0; o >>= 1) {
            if (t < o) dsm[t] += dsm[t + o];
            __syncthreads();
        }
        if (t == 0) p1[slot] = dsm[0];
    }
}

// ===========================================================================
// 128x128 kernel (R7-proven) — used for enc3 (N=128) and koopman MLP.
// ===========================================================================
template <bool TANH, bool OUTF16>
__global__ __launch_bounds__(256) void k_gemm_f16(const f16* __restrict__ A,
                                                  const f16* __restrict__ Wt,
                                                  const float* __restrict__ bias,
                                                  void* __restrict__ Cv,
                                                  int M, int N, int K)
{
    __shared__ __align__(16) f16 As[128][32];
    __shared__ __align__(16) f16 Bs[128][32];

    const int t  = threadIdx.x;
    const int l  = t & 63;
    const int wv = t >> 6;
    const int wr = wv >> 1, wc = wv & 1;
    const int lm = l & 15, lk = l >> 4;
    const int bm = blockIdx.y, bn = blockIdx.x;

    const f16* Ab = A  + (size_t)bm * 128 * K;
    const f16* Bb = Wt + (size_t)bn * 128 * K;
    char* sA = (char*)&As[0][0];
    char* sB = (char*)&Bs[0][0];
    const int wbase = wv * 64;

    f32x4 acc[4][4] = {};

    for (int k0 = 0; k0 < K; k0 += 32) {
#pragma unroll
        for (int r = 0; r < 2; ++r) {
            const int c = r * 256 + t;
            const size_t goff = (size_t)(c >> 2) * K + (size_t)k0 + (size_t)(c & 3) * 8;
            gl_lds16(Ab + goff, sA + (size_t)(r * 256 + wbase) * 16);
            gl_lds16(Bb + goff, sB + (size_t)(r * 256 + wbase) * 16);
        }
        __syncthreads();

        f16x8 af[4], bf[4];
#pragma unroll
        for (int i = 0; i < 4; ++i) {
            af[i] = *reinterpret_cast<const f16x8*>(&As[wr * 64 + i * 16 + lm][lk * 8]);
            bf[i] = *reinterpret_cast<const f16x8*>(&Bs[wc * 64 + i * 16 + lm][lk * 8]);
        }
#pragma unroll
        for (int i = 0; i < 4; ++i)
#pragma unroll
            for (int j = 0; j < 4; ++j)
                acc[i][j] = __builtin_amdgcn_mfma_f32_16x16x32_f16(af[i], bf[j], acc[i][j], 0, 0, 0);
        __syncthreads();
    }

    const int row0 = bm * 128 + wr * 64;
    const int col0 = bn * 128 + wc * 64;
#pragma unroll
    for (int j = 0; j < 4; ++j) {
        const int col = col0 + j * 16 + lm;
        const float bv = bias[col];
#pragma unroll
        for (int i = 0; i < 4; ++i)
#pragma unroll
            for (int q = 0; q < 4; ++q) {
                const int row = row0 + i * 16 + lk * 4 + q;
                float v = acc[i][j][q] + bv;
                if (TANH) v = fast_tanh(v);
                if (OUTF16) ((f16*)Cv)[(size_t)row * N + col] = (f16)v;
                else        ((float*)Cv)[(size_t)row * N + col] = v;
            }
    }
}

// ---------------------------------------------------------------------------
__global__ __launch_bounds__(256) void k_wt(const float* __restrict__ W,
                                            f16* __restrict__ Wt, int K, int N)
{
    __shared__ float tl[32][33];
    const int n0 = blockIdx.x * 32, k0 = blockIdx.y * 32;
    const int tx = threadIdx.x & 31, ty = threadIdx.x >> 5;
#pragma unroll
    for (int i = 0; i < 32; i += 8)
        tl[ty + i][tx] = W[(size_t)(k0 + ty + i) * N + n0 + tx];
    __syncthreads();
#pragma unroll
    for (int i = 0; i < 32; i += 8)
        Wt[(size_t)(n0 + ty + i) * K + k0 + tx] = (f16)tl[tx][ty + i];
}

__global__ __launch_bounds__(256) void k_gather_all(const float* __restrict__ win,
                                                    f16* __restrict__ out, int g0, int nrows)
{
    const int i = blockIdx.x * 256 + threadIdx.x;
    if (i >= nrows * 64) return;
    const int r = i >> 6, c8 = i & 63;
    const float* s = win + ((size_t)(g0 + r)) * 512 + c8 * 8;
    const float4 v0 = *reinterpret_cast<const float4*>(s);
    const float4 v1 = *reinterpret_cast<const float4*>(s + 4);
    f16x8 o;
    o[0] = (f16)v0.x; o[1] = (f16)v0.y; o[2] = (f16)v0.z; o[3] = (f16)v0.w;
    o[4] = (f16)v1.x; o[5] = (f16)v1.y; o[6] = (f16)v1.z; o[7] = (f16)v1.w;
    *reinterpret_cast<f16x8*>(out + (size_t)r * 512 + c8 * 8) = o;
}

__global__ __launch_bounds__(256) void k_gather_z0(const float* __restrict__ cZfull,
                                                   float* __restrict__ z0f32,
                                                   f16* __restrict__ z0f16)
{
    const int i = blockIdx.x * 256 + threadIdx.x;     // 512*32 float4s
    if (i >= 512 * 32) return;
    const int b = i >> 5, c4 = i & 31;
    const float4 v = *reinterpret_cast<const float4*>(cZfull + (size_t)b * 16384 + c4 * 4);
    *reinterpret_cast<float4*>(z0f32 + (size_t)b * 128 + c4 * 4) = v;
    f16x4 o;
    o[0] = (f16)v.x; o[1] = (f16)v.y; o[2] = (f16)v.z; o[3] = (f16)v.w;
    *reinterpret_cast<f16x4*>(z0f16 + (size_t)b * 128 + c4 * 4) = o;
}

__global__ __launch_bounds__(256) void k_koop(const float* __restrict__ cZ,
                                              const float* __restrict__ z0,
                                              const float* __restrict__ pK,
                                              int g0, int nrows,
                                              f16* __restrict__ decin,
                                              double* __restrict__ p0)
{
    const int idx = blockIdx.x * 256 + threadIdx.x;
    double s = 0.0;
    if (idx < nrows * 16) {
        const int r = idx >> 4, c8 = idx & 15;
        const int g = g0 + r;
        const int tt = g & 127;
        const int bb = g >> 7;

        float zt[8];
        *reinterpret_cast<float4*>(zt)     = *reinterpret_cast<const float4*>(cZ + (size_t)r * 128 + c8 * 8);
        *reinterpret_cast<float4*>(zt + 4) = *reinterpret_cast<const float4*>(cZ + (size_t)r * 128 + c8 * 8 + 4);

        float ov[8];
        if (tt == 0) {
#pragma unroll
            for (int k = 0; k < 8; ++k) ov[k] = zt[k];
        } else {
            float zz[8], qq[8];
            *reinterpret_cast<float4*>(zz)     = *reinterpret_cast<const float4*>(z0 + (size_t)bb * 128 + c8 * 8);
            *reinterpret_cast<float4*>(zz + 4) = *reinterpret_cast<const float4*>(z0 + (size_t)bb * 128 + c8 * 8 + 4);
            *reinterpret_cast<float4*>(qq)     = *reinterpret_cast<const float4*>(pK + (size_t)bb * 128 + c8 * 8);
            *reinterpret_cast<float4*>(qq + 4) = *reinterpret_cast<const float4*>(pK + (size_t)bb * 128 + c8 * 8 + 4);
            const float tf = KDT * (float)tt;
#pragma unroll
            for (int pr = 0; pr < 4; ++pr) {
                const float e = __expf(qq[2 * pr] * tf);
                float sn, cs;
                __sincosf(qq[2 * pr + 1] * tf, &sn, &cs);
                const float zx = zz[2 * pr], zy = zz[2 * pr + 1];
                const float a = e * (cs * zx - sn * zy);
                const float b = e * (sn * zx + cs * zy);
                ov[2 * pr] = a; ov[2 * pr + 1] = b;
                const float d0 = a - zt[2 * pr], d1 = b - zt[2 * pr + 1];
                s += (double)d0 * d0 + (double)d1 * d1;
            }
        }
        f16x8 o;
#pragma unroll
        for (int k = 0; k < 8; ++k) o[k] = (f16)ov[k];
        *reinterpret_cast<f16x8*>(decin + (size_t)r * 128 + c8 * 8) = o;
    }

    __shared__ double sm[256];
    sm[threadIdx.x] = s;
    __syncthreads();
    for (int off = 128; off > 0; off >>= 1) {
        if (threadIdx.x < (unsigned)off) sm[threadIdx.x] += sm[threadIdx.x + off];
        __syncthreads();
    }
    if (threadIdx.x == 0) p0[blockIdx.x] = sm[0];
}

__global__ __launch_bounds__(256) void k_finalize(const double* __restrict__ pb,
                                                  float* __restrict__ out)
{
    __shared__ double sm[256];
    const int t = threadIdx.x;
    double a0 = 0.0, a1 = 0.0, a2 = 0.0;
    for (int i = t; i < 4096; i += 256) a0 += pb[PB_LIN + i];
    for (int i = t; i < 2048; i += 256) a1 += pb[PB_REC + i];
    for (int i = t; i < 2048; i += 256) a2 += pb[PB_PRED + i];

    double r[3];
    double v[3] = {a0, a1, a2};
    for (int k = 0; k < 3; ++k) {
        sm[t] = v[k];
        __syncthreads();
        for (int o = 128; o > 0; o >>= 1) {
            if (t < o) sm[t] += sm[t + o];
            __syncthreads();
        }
        r[k] = sm[0];
        __syncthreads();
    }
    if (t == 0) {
        const double linear = r[0] / (65024.0 * 128.0);
        const double recon  = r[1] / (512.0 * 512.0);
        const double pred   = r[2] / (65024.0 * 512.0);
        out[0] = (float)(recon + linear + pred);
        out[1] = (float)recon;
        out[2] = (float)linear;
        out[3] = (float)pred;
    }
}

// ---------------------------------------------------------------------------
extern "C" void kernel_launch(void* const* d_in, const int* in_sizes, int n_in,
                              void* d_out, int out_size, void* d_ws, size_t ws_size,
                              hipStream_t stream)
{
    const float* window = (const float*)d_in[0];
    const float* eW1 = (const float*)d_in[1];
    const float* eb1 = (const float*)d_in[2];
    const float* eW2 = (const float*)d_in[3];
    const float* eb2 = (const float*)d_in[4];
    const float* eW3 = (const float*)d_in[5];
    const float* eb3 = (const float*)d_in[6];
    const float* dW1 = (const float*)d_in[7];
    const float* db1 = (const float*)d_in[8];
    const float* dW2 = (const float*)d_in[9];
    const float* db2 = (const float*)d_in[10];
    const float* dW3 = (const float*)d_in[11];
    const float* db3 = (const float*)d_in[12];
    const float* kW1 = (const float*)d_in[13];
    const float* kb1 = (const float*)d_in[14];
    const float* kW2 = (const float*)d_in[15];
    const float* kb2 = (const float*)d_in[16];
    float* out = (float*)d_out;
    (void)in_sizes; (void)n_in; (void)out_size;

    // chunking: un-chunked if workspace is big enough (~378 MB needed)
    const int nch = (ws_size >= (450ull << 20)) ? 1 : 4;
    const int MC  = 65536 / nch;

    char* p = (char*)d_ws;
    size_t off = 0;
    auto takeB = [&](size_t bytes) -> char* {
        char* r = p + off;
        off += (bytes + 255) & ~(size_t)255;
        return r;
    };
    double* pb = (double*)takeB(PB_TOTAL * 8);
    f16* eW1t = (f16*)takeB((size_t)512 * 1024 * 2);
    f16* eW2t = (f16*)takeB((size_t)1024 * 1024 * 2);
    f16* eW3t = (f16*)takeB((size_t)1024 * 128 * 2);
    f16* dW1t = (f16*)takeB((size_t)128 * 1024 * 2);
    f16* dW2t = (f16*)takeB((size_t)1024 * 1024 * 2);
    f16* dW3t = (f16*)takeB((size_t)1024 * 512 * 2);
    f16* kW1t = (f16*)takeB((size_t)128 * 128 * 2);
    f16* kW2t = (f16*)takeB((size_t)128 * 128 * 2);
    float* z0f32 = (float*)takeB((size_t)65536 * 4);
    f16* z0f16 = (f16*)takeB((size_t)65536 * 2);
    f16* hK = (f16*)takeB((size_t)65536 * 2);
    float* pKbuf = (float*)takeB((size_t)65536 * 4);
    float* cZfull = (float*)takeB((size_t)65536 * 128 * 4);   // 32 MB
    f16* aIn  = (f16*)takeB((size_t)MC * 512 * 2);
    f16* cH1  = (f16*)takeB((size_t)MC * 1024 * 2);
    f16* cH2  = (f16*)takeB((size_t)MC * 1024 * 2);
    f16* decin = (f16*)takeB((size_t)MC * 128 * 2);

    hipMemsetAsync(pb, 0, PB_TOTAL * 8, stream);

    auto G256 = [&](const f16* A, const f16* Wt, const float* b, void* C,
                    int M, int N, int K, bool tanh_, bool f16out) {
        dim3 grid(N / 256, M / 256);
        if (tanh_)       k_gemm256<0, true,  true ><<<grid, 512, 0, stream>>>(A, Wt, b, C, M, N, K, nullptr, 0, nullptr, nullptr);
        else if (f16out) k_gemm256<0, false, true ><<<grid, 512, 0, stream>>>(A, Wt, b, C, M, N, K, nullptr, 0, nullptr, nullptr);
        else             k_gemm256<0, false, false><<<grid, 512, 0, stream>>>(A, Wt, b, C, M, N, K, nullptr, 0, nullptr, nullptr);
    };
    auto G128 = [&](const f16* A, const f16* Wt, const float* b, void* C,
                    int M, int N, int K, bool tanh_, bool f16out) {
        dim3 grid(N / 128, M / 128);
        if (tanh_)       k_gemm_f16<true,  true ><<<grid, 256, 0, stream>>>(A, Wt, b, C, M, N, K);
        else if (f16out) k_gemm_f16<false, true ><<<grid, 256, 0, stream>>>(A, Wt, b, C, M, N, K);
        else             k_gemm_f16<false, false><<<grid, 256, 0, stream>>>(A, Wt, b, C, M, N, K);
    };
    auto WT = [&](const float* W, f16* Wt, int K, int N) {
        k_wt<<<dim3(N / 32, K / 32), 256, 0, stream>>>(W, Wt, K, N);
    };

    // weight prep
    WT(eW1, eW1t, 512, 1024);  WT(eW2, eW2t, 1024, 1024); WT(eW3, eW3t, 1024, 128);
    WT(dW1, dW1t, 128, 1024);  WT(dW2, dW2t, 1024, 1024); WT(dW3, dW3t, 1024, 512);
    WT(kW1, kW1t, 128, 128);   WT(kW2, kW2t, 128, 128);

    // Phase A: encoder over all rows -> cZfull
    for (int c = 0; c < nch; ++c) {
        const int g0 = c * MC;
        k_gather_all<<<MC * 64 / 256, 256, 0, stream>>>(window, aIn, g0, MC);
        G256(aIn, eW1t, eb1, cH1, MC, 1024, 512, true, true);
        G256(cH1, eW2t, eb2, cH2, MC, 1024, 1024, true, true);
        G128(cH2, eW3t, eb3, cZfull + (size_t)g0 * 128, MC, 128, 1024, false, false);
    }

    // Phase B: z0 + koopman params (tiny, 128^2 kernel)
    k_gather_z0<<<64, 256, 0, stream>>>(cZfull, z0f32, z0f16);
    G128(z0f16, kW1t, kb1, hK, 512, 128, 128, true, true);
    G128(hK,    kW2t, kb2, pKbuf, 512, 128, 128, false, false);

    // Phase C: koopman rollout + decoder + losses
    for (int c = 0; c < nch; ++c) {
        const int g0 = c * MC;
        k_koop<<<MC / 16, 256, 0, stream>>>(cZfull + (size_t)g0 * 128, z0f32, pKbuf,
                                            g0, MC, decin, pb + PB_LIN + (g0 >> 4));
        G256(decin, dW1t, db1, cH1, MC, 1024, 128, true, true);
        G256(cH1,   dW2t, db2, cH2, MC, 1024, 1024, true, true);
        k_gemm256<2, false, false><<<dim3(2, MC / 256), 512, 0, stream>>>(
            cH2, dW3t, db3, nullptr, MC, 512, 1024,
            window, g0, pb + PB_REC, pb + PB_PRED);
    }

    k_finalize<<<1, 256, 0, stream>>>(pb, out);
}

// Round 9
// 1197.267 us; speedup vs baseline: 2.4746x; 2.4746x over previous
//
#include <hip/hip_runtime.h>
#include <cstddef>
#include <cstdint>

// DynamicAutoencoder — Round 9: R7 scaffold + two targeted 128^2-GEMM fixes.
//   (1) T2 both-sides LDS swizzle for BK=32 (slot ^= (row>>1)&3):
//       linear gl_lds dest, pre-swizzled global source, swizzled ds_read.
//       Kills the 8-way bank conflict R7 measured (4.19M/dispatch).
//   (2) T1 XCD-chunked block swizzle (guarded nwg%8==0): contiguous row-panels
//       per XCD -> A-panel L2 reuse (FETCH 133MB -> ~60MB predicted).
// R8's 256^2 kernel removed (acc spilled to scratch: 2.4GB/dispatch writes).
//   Phase A (x4): gather -> enc1 -> enc2 -> enc3 -> cZfull
//   Phase B: z0 extract; koopman MLP -> pK
//   Phase C (x4): k_koop -> dec1 -> dec2 -> dec3(fused recon/pred loss)

#define KDT 0.01f
#define CH 16384
#define NCHUNK 4

typedef _Float16 f16;
typedef f16 f16x8 __attribute__((ext_vector_type(8)));
typedef f16 f16x4 __attribute__((ext_vector_type(4)));
typedef float f32x4 __attribute__((ext_vector_type(4)));

typedef __attribute__((address_space(1))) const unsigned int gu32;
typedef __attribute__((address_space(3))) unsigned int lu32;

__device__ __forceinline__ void gl_lds16(const void* g, void* l) {
    __builtin_amdgcn_global_load_lds((gu32*)g, (lu32*)l, 16, 0, 0);
}

__device__ __forceinline__ float fast_tanh(float x) {
    x = fminf(fmaxf(x, -15.f), 15.f);
    const float e = __expf(2.f * x);
    return (e - 1.f) / (e + 1.f);
}

// partial-sum slots (doubles): lin [0,4096) | rec [4096,6144) | pred [6144,8192)
#define PB_LIN 0
#define PB_REC 4096
#define PB_PRED 6144
#define PB_TOTAL 8192

// ---------------------------------------------------------------------------
// GEMM: C = act(A @ Wt^T + bias). A: [M][K] f16, Wt: [N][K] f16.
// 128x128 tile, BK=32, 4 waves, mfma_f32_16x16x32_f16.
// LDS layout: As[row][slot*8..], slot in [0,4) of 16B; LDS slot s holds
// global slot (s ^ ((row>>1)&3)). MODE 0: store. MODE 2: fused loss vs window.
// ---------------------------------------------------------------------------
template <int MODE, bool TANH, bool OUTF16>
__global__ __launch_bounds__(256) void k_gemm_f16(const f16* __restrict__ A,
                                                  const f16* __restrict__ Wt,
                                                  const float* __restrict__ bias,
                                                  void* __restrict__ Cv,
                                                  int M, int N, int K,
                                                  const float* __restrict__ win,
                                                  int g0,
                                                  double* __restrict__ p0,
                                                  double* __restrict__ p1)
{
    __shared__ __align__(16) f16 As[128][32];
    __shared__ __align__(16) f16 Bs[128][32];
    __shared__ double sm[256];

    const int t  = threadIdx.x;
    const int l  = t & 63;
    const int wv = t >> 6;
    const int wr = wv >> 1, wc = wv & 1;
    const int lm = l & 15, lk = l >> 4;

    // T1: XCD-chunked swizzle (identity when nwg not a multiple of 8)
    const int gx = gridDim.x;
    const int nwg = gx * gridDim.y;
    const int orig = blockIdx.y * gx + blockIdx.x;
    int tile = orig;
    if ((nwg & 7) == 0) tile = (orig & 7) * (nwg >> 3) + (orig >> 3);
    const int bm = tile / gx;
    const int bn = tile % gx;

    const f16* Ab = A  + (size_t)bm * 128 * K;
    const f16* Bb = Wt + (size_t)bn * 128 * K;
    char* sA = (char*)&As[0][0];
    char* sB = (char*)&Bs[0][0];

    // fragment read slot XOR: rows in a 16-row group have (row>>1)&3 == (lm>>1)&3
    const int rswz = (lm >> 1) & 3;
    const int rdA = (lk ^ rswz) * 16;

    f32x4 acc[4][4] = {};

    for (int k0 = 0; k0 < K; k0 += 32) {
        // stage 128x32 tiles: 512 16B chunks each; linear LDS dest,
        // source slot pre-swizzled so read-side XOR sees linear columns.
#pragma unroll
        for (int r = 0; r < 2; ++r) {
            const int c = r * 256 + t;
            const int row = c >> 2;
            const int sslot = (c & 3) ^ ((row >> 1) & 3);
            const size_t goff = (size_t)row * K + (size_t)k0 + (size_t)sslot * 8;
            gl_lds16(Ab + goff, sA + (size_t)c * 16);
            gl_lds16(Bb + goff, sB + (size_t)c * 16);
        }
        __syncthreads();

        f16x8 af[4], bf[4];
#pragma unroll
        for (int i = 0; i < 4; ++i) {
            af[i] = *reinterpret_cast<const f16x8*>(sA + (wr * 64 + i * 16 + lm) * 64 + rdA);
            bf[i] = *reinterpret_cast<const f16x8*>(sB + (wc * 64 + i * 16 + lm) * 64 + rdA);
        }
#pragma unroll
        for (int i = 0; i < 4; ++i)
#pragma unroll
            for (int j = 0; j < 4; ++j)
                acc[i][j] = __builtin_amdgcn_mfma_f32_16x16x32_f16(af[i], bf[j], acc[i][j], 0, 0, 0);
        __syncthreads();
    }

    // C/D fragment: col = lane&15 (+j*16), row = (lane>>4)*4 + q (+i*16)
    const int col0 = bn * 128 + wc * 64;

    if (MODE == 0) {
        const int row0 = bm * 128 + wr * 64;
#pragma unroll
        for (int j = 0; j < 4; ++j) {
            const int col = col0 + j * 16 + lm;
            const float bv = bias[col];
#pragma unroll
            for (int i = 0; i < 4; ++i)
#pragma unroll
                for (int q = 0; q < 4; ++q) {
                    const int row = row0 + i * 16 + lk * 4 + q;
                    float v = acc[i][j][q] + bv;
                    if (TANH) v = fast_tanh(v);
                    if (OUTF16) ((f16*)Cv)[(size_t)row * N + col] = (f16)v;
                    else        ((float*)Cv)[(size_t)row * N + col] = v;
                }
        }
    } else {  // MODE 2: loss vs window, no store
        double s0 = 0.0, s1 = 0.0;
#pragma unroll
        for (int i = 0; i < 4; ++i) {
#pragma unroll
            for (int q = 0; q < 4; ++q) {
                const int rl = bm * 128 + wr * 64 + i * 16 + lk * 4 + q;
                const int g  = g0 + rl;
                const int tt = g & 127;
#pragma unroll
                for (int j = 0; j < 4; ++j) {
                    const int col = col0 + j * 16 + lm;
                    const float v = acc[i][j][q] + bias[col];
                    const float d = v - win[(size_t)g * 512 + col];
                    if (tt == 0) s0 += (double)d * d;
                    else         s1 += (double)d * d;
                }
            }
        }
        sm[t] = s0;
        __syncthreads();
        for (int o = 128; o > 0; o >>= 1) {
            if (t < o) sm[t] += sm[t + o];
            __syncthreads();
        }
        if (t == 0) p0[tile] = sm[0];
        __syncthreads();
        sm[t] = s1;
        __syncthreads();
        for (int o = 128; o > 0; o >>= 1) {
            if (t < o) sm[t] += sm[t + o];
            __syncthreads();
        }
        if (t == 0) p1[tile] = sm[0];
    }
}

// ---------------------------------------------------------------------------
// Weight transpose+convert: W f32 [K][N] -> Wt f16 [N][K].
// ---------------------------------------------------------------------------
__global__ __launch_bounds__(256) void k_wt(const float* __restrict__ W,
                                            f16* __restrict__ Wt, int K, int N)
{
    __shared__ float tl[32][33];
    const int n0 = blockIdx.x * 32, k0 = blockIdx.y * 32;
    const int tx = threadIdx.x & 31, ty = threadIdx.x >> 5;
#pragma unroll
    for (int i = 0; i < 32; i += 8)
        tl[ty + i][tx] = W[(size_t)(k0 + ty + i) * N + n0 + tx];
    __syncthreads();
#pragma unroll
    for (int i = 0; i < 32; i += 8)
        Wt[(size_t)(n0 + ty + i) * K + k0 + tx] = (f16)tl[tx][ty + i];
}

__global__ __launch_bounds__(256) void k_gather_all(const float* __restrict__ win,
                                                    f16* __restrict__ out, int g0)
{
    const int i = blockIdx.x * 256 + threadIdx.x;     // CH*64 8-elem chunks
    if (i >= CH * 64) return;
    const int r = i >> 6, c8 = i & 63;
    const float* s = win + ((size_t)(g0 + r)) * 512 + c8 * 8;
    const float4 v0 = *reinterpret_cast<const float4*>(s);
    const float4 v1 = *reinterpret_cast<const float4*>(s + 4);
    f16x8 o;
    o[0] = (f16)v0.x; o[1] = (f16)v0.y; o[2] = (f16)v0.z; o[3] = (f16)v0.w;
    o[4] = (f16)v1.x; o[5] = (f16)v1.y; o[6] = (f16)v1.z; o[7] = (f16)v1.w;
    *reinterpret_cast<f16x8*>(out + (size_t)r * 512 + c8 * 8) = o;
}

__global__ __launch_bounds__(256) void k_gather_z0(const float* __restrict__ cZfull,
                                                   float* __restrict__ z0f32,
                                                   f16* __restrict__ z0f16)
{
    const int i = blockIdx.x * 256 + threadIdx.x;     // 512*32 float4s
    if (i >= 512 * 32) return;
    const int b = i >> 5, c4 = i & 31;
    const float4 v = *reinterpret_cast<const float4*>(cZfull + (size_t)b * 16384 + c4 * 4);
    *reinterpret_cast<float4*>(z0f32 + (size_t)b * 128 + c4 * 4) = v;
    f16x4 o;
    o[0] = (f16)v.x; o[1] = (f16)v.y; o[2] = (f16)v.z; o[3] = (f16)v.w;
    *reinterpret_cast<f16x4*>(z0f16 + (size_t)b * 128 + c4 * 4) = o;
}

// ---------------------------------------------------------------------------
// Koopman closed form + linear loss + decin build. 16 threads/row.
// ---------------------------------------------------------------------------
__global__ __launch_bounds__(256) void k_koop(const float* __restrict__ cZ,
                                              const float* __restrict__ z0,
                                              const float* __restrict__ pK,
                                              int g0,
                                              f16* __restrict__ decin,
                                              double* __restrict__ p0)
{
    const int idx = blockIdx.x * 256 + threadIdx.x;   // CH*16
    const int r = idx >> 4, c8 = idx & 15;
    const int g = g0 + r;
    const int tt = g & 127;
    const int bb = g >> 7;

    float zt[8];
    *reinterpret_cast<float4*>(zt)     = *reinterpret_cast<const float4*>(cZ + (size_t)r * 128 + c8 * 8);
    *reinterpret_cast<float4*>(zt + 4) = *reinterpret_cast<const float4*>(cZ + (size_t)r * 128 + c8 * 8 + 4);

    double s = 0.0;
    float ov[8];
    if (tt == 0) {
#pragma unroll
        for (int k = 0; k < 8; ++k) ov[k] = zt[k];
    } else {
        float zz[8], qq[8];
        *reinterpret_cast<float4*>(zz)     = *reinterpret_cast<const float4*>(z0 + (size_t)bb * 128 + c8 * 8);
        *reinterpret_cast<float4*>(zz + 4) = *reinterpret_cast<const float4*>(z0 + (size_t)bb * 128 + c8 * 8 + 4);
        *reinterpret_cast<float4*>(qq)     = *reinterpret_cast<const float4*>(pK + (size_t)bb * 128 + c8 * 8);
        *reinterpret_cast<float4*>(qq + 4) = *reinterpret_cast<const float4*>(pK + (size_t)bb * 128 + c8 * 8 + 4);
        const float tf = KDT * (float)tt;
#pragma unroll
        for (int pr = 0; pr < 4; ++pr) {
            const float e = __expf(qq[2 * pr] * tf);
            float sn, cs;
            __sincosf(qq[2 * pr + 1] * tf, &sn, &cs);
            const float zx = zz[2 * pr], zy = zz[2 * pr + 1];
            const float a = e * (cs * zx - sn * zy);
            const float b = e * (sn * zx + cs * zy);
            ov[2 * pr] = a; ov[2 * pr + 1] = b;
            const float d0 = a - zt[2 * pr], d1 = b - zt[2 * pr + 1];
            s += (double)d0 * d0 + (double)d1 * d1;
        }
    }
    f16x8 o;
#pragma unroll
    for (int k = 0; k < 8; ++k) o[k] = (f16)ov[k];
    *reinterpret_cast<f16x8*>(decin + (size_t)r * 128 + c8 * 8) = o;

    __shared__ double sm[256];
    sm[threadIdx.x] = s;
    __syncthreads();
    for (int off = 128; off > 0; off >>= 1) {
        if (threadIdx.x < (unsigned)off) sm[threadIdx.x] += sm[threadIdx.x + off];
        __syncthreads();
    }
    if (threadIdx.x == 0) p0[blockIdx.x] = sm[0];
}

// ---------------------------------------------------------------------------
__global__ __launch_bounds__(256) void k_finalize(const double* __restrict__ pb,
                                                  float* __restrict__ out)
{
    __shared__ double sm[256];
    const int t = threadIdx.x;
    double a0 = 0.0, a1 = 0.0, a2 = 0.0;
    for (int i = t; i < 4096; i += 256) a0 += pb[PB_LIN + i];
    for (int i = t; i < 2048; i += 256) a1 += pb[PB_REC + i];
    for (int i = t; i < 2048; i += 256) a2 += pb[PB_PRED + i];

    double r[3];
    double v[3] = {a0, a1, a2};
    for (int k = 0; k < 3; ++k) {
        sm[t] = v[k];
        __syncthreads();
        for (int o = 128; o > 0; o >>= 1) {
            if (t < o) sm[t] += sm[t + o];
            __syncthreads();
        }
        r[k] = sm[0];
        __syncthreads();
    }
    if (t == 0) {
        const double linear = r[0] / (65024.0 * 128.0);
        const double recon  = r[1] / (512.0 * 512.0);
        const double pred   = r[2] / (65024.0 * 512.0);
        out[0] = (float)(recon + linear + pred);
        out[1] = (float)recon;
        out[2] = (float)linear;
        out[3] = (float)pred;
    }
}

// ---------------------------------------------------------------------------
extern "C" void kernel_launch(void* const* d_in, const int* in_sizes, int n_in,
                              void* d_out, int out_size, void* d_ws, size_t ws_size,
                              hipStream_t stream)
{
    const float* window = (const float*)d_in[0];
    const float* eW1 = (const float*)d_in[1];
    const float* eb1 = (const float*)d_in[2];
    const float* eW2 = (const float*)d_in[3];
    const float* eb2 = (const float*)d_in[4];
    const float* eW3 = (const float*)d_in[5];
    const float* eb3 = (const float*)d_in[6];
    const float* dW1 = (const float*)d_in[7];
    const float* db1 = (const float*)d_in[8];
    const float* dW2 = (const float*)d_in[9];
    const float* db2 = (const float*)d_in[10];
    const float* dW3 = (const float*)d_in[11];
    const float* db3 = (const float*)d_in[12];
    const float* kW1 = (const float*)d_in[13];
    const float* kb1 = (const float*)d_in[14];
    const float* kW2 = (const float*)d_in[15];
    const float* kb2 = (const float*)d_in[16];
    float* out = (float*)d_out;
    (void)in_sizes; (void)n_in; (void)out_size; (void)ws_size;

    char* p = (char*)d_ws;
    size_t off = 0;
    auto takeB = [&](size_t bytes) -> char* {
        char* r = p + off;
        off += (bytes + 255) & ~(size_t)255;
        return r;
    };
    double* pb = (double*)takeB(PB_TOTAL * 8);
    f16* eW1t = (f16*)takeB((size_t)512 * 1024 * 2);
    f16* eW2t = (f16*)takeB((size_t)1024 * 1024 * 2);
    f16* eW3t = (f16*)takeB((size_t)1024 * 128 * 2);
    f16* dW1t = (f16*)takeB((size_t)128 * 1024 * 2);
    f16* dW2t = (f16*)takeB((size_t)1024 * 1024 * 2);
    f16* dW3t = (f16*)takeB((size_t)1024 * 512 * 2);
    f16* kW1t = (f16*)takeB((size_t)128 * 128 * 2);
    f16* kW2t = (f16*)takeB((size_t)128 * 128 * 2);
    float* z0f32 = (float*)takeB((size_t)65536 * 4);
    f16* z0f16 = (f16*)takeB((size_t)65536 * 2);
    f16* hK = (f16*)takeB((size_t)65536 * 2);
    float* pKbuf = (float*)takeB((size_t)65536 * 4);
    float* cZfull = (float*)takeB((size_t)65536 * 128 * 4);   // 32 MB
    f16* cIn = (f16*)takeB((size_t)CH * 512 * 2);
    f16* cH1 = (f16*)takeB((size_t)CH * 1024 * 2);
    f16* cH2 = (f16*)takeB((size_t)CH * 1024 * 2);
    f16* decin = (f16*)takeB((size_t)CH * 128 * 2);

    hipMemsetAsync(pb, 0, PB_TOTAL * 8, stream);

    auto G = [&](const f16* A, const f16* Wt, const float* b, void* C,
                 int M, int N, int K, bool tanh_, bool f16out) {
        dim3 grid(N / 128, M / 128);
        if (tanh_)       k_gemm_f16<0, true,  true ><<<grid, 256, 0, stream>>>(A, Wt, b, C, M, N, K, nullptr, 0, nullptr, nullptr);
        else if (f16out) k_gemm_f16<0, false, true ><<<grid, 256, 0, stream>>>(A, Wt, b, C, M, N, K, nullptr, 0, nullptr, nullptr);
        else             k_gemm_f16<0, false, false><<<grid, 256, 0, stream>>>(A, Wt, b, C, M, N, K, nullptr, 0, nullptr, nullptr);
    };
    auto WT = [&](const float* W, f16* Wt, int K, int N) {
        k_wt<<<dim3(N / 32, K / 32), 256, 0, stream>>>(W, Wt, K, N);
    };

    // weight prep
    WT(eW1, eW1t, 512, 1024);  WT(eW2, eW2t, 1024, 1024); WT(eW3, eW3t, 1024, 128);
    WT(dW1, dW1t, 128, 1024);  WT(dW2, dW2t, 1024, 1024); WT(dW3, dW3t, 1024, 512);
    WT(kW1, kW1t, 128, 128);   WT(kW2, kW2t, 128, 128);

    // Phase A: encoder over all rows -> cZfull
    for (int c = 0; c < NCHUNK; ++c) {
        const int g0 = c * CH;
        k_gather_all<<<CH * 64 / 256, 256, 0, stream>>>(window, cIn, g0);
        G(cIn, eW1t, eb1, cH1, CH, 1024, 512, true, true);
        G(cH1, eW2t, eb2, cH2, CH, 1024, 1024, true, true);
        G(cH2, eW3t, eb3, cZfull + (size_t)g0 * 128, CH, 128, 1024, false, false);
    }

    // Phase B: z0 + koopman params
    k_gather_z0<<<64, 256, 0, stream>>>(cZfull, z0f32, z0f16);
    G(z0f16, kW1t, kb1, hK, 512, 128, 128, true, true);
    G(hK,    kW2t, kb2, pKbuf, 512, 128, 128, false, false);

    // Phase C: koopman rollout + decoder + losses
    for (int c = 0; c < NCHUNK; ++c) {
        const int g0 = c * CH;
        k_koop<<<CH * 16 / 256, 256, 0, stream>>>(cZfull + (size_t)g0 * 128, z0f32, pKbuf,
                                                  g0, decin, pb + PB_LIN + c * 1024);
        G(decin, dW1t, db1, cH1, CH, 1024, 128, true, true);
        G(cH1,   dW2t, db2, cH2, CH, 1024, 1024, true, true);
        k_gemm_f16<2, false, false><<<dim3(4, CH / 128), 256, 0, stream>>>(
            cH2, dW3t, db3, nullptr, CH, 512, 1024,
            window, g0, pb + PB_REC + c * 512, pb + PB_PRED + c * 512);
    }

    k_finalize<<<1, 256, 0, stream>>>(pb, out);
}

// Round 10
// 1040.089 us; speedup vs baseline: 2.8486x; 1.1511x over previous
//
#include <hip/hip_runtime.h>
#include <cstddef>
#include <cstdint>

// DynamicAutoencoder — Round 10: un-chunked (ws=512MiB confirmed), BK=64,
// compile-time N/K templates, R8-proven 8-slot both-sides LDS swizzle
// (measured 0 bank conflicts), T1 XCD swizzle. Same 2-barrier schedule as the
// verified R7/R9 kernel (no sync-structure edits).
//   Phase A: gather(all) -> enc1 -> enc2 -> enc3 -> cZfull
//   Phase B: z0 extract -> koop MLP -> pK
//   Phase C: k_koop -> dec1 -> dec2 -> dec3(fused recon/pred loss)

#define KDT 0.01f

typedef _Float16 f16;
typedef f16 f16x8 __attribute__((ext_vector_type(8)));
typedef f16 f16x4 __attribute__((ext_vector_type(4)));
typedef float f32x4 __attribute__((ext_vector_type(4)));

typedef __attribute__((address_space(1))) const unsigned int gu32;
typedef __attribute__((address_space(3))) unsigned int lu32;

__device__ __forceinline__ void gl_lds16(const void* g, void* l) {
    __builtin_amdgcn_global_load_lds((gu32*)g, (lu32*)l, 16, 0, 0);
}

__device__ __forceinline__ float fast_tanh(float x) {
    x = fminf(fmaxf(x, -15.f), 15.f);
    const float e = __expf(2.f * x);
    return (e - 1.f) / (e + 1.f);
}

// partial-sum slots (doubles): lin [0,4096) | rec [4096,6144) | pred [6144,8192)
#define PB_LIN 0
#define PB_REC 4096
#define PB_PRED 6144
#define PB_TOTAL 8192

// ---------------------------------------------------------------------------
// GEMM: C = act(A @ Wt^T + bias). A: [M][K] f16, Wt: [N][K] f16. N,K constexpr.
// 128x128 tile, BK=64, 4 waves, mfma_f32_16x16x32_f16.
// LDS: [128 rows][8 slots of 16B]; LDS slot s of row r holds global slot
// s ^ (r&7) (linear gl_lds dest, pre-swizzled source, swizzled read — rule #21,
// R8-measured 0 conflicts). MODE 0: store. MODE 2: fused loss vs window.
// ---------------------------------------------------------------------------
template <int MODE, bool TANH, bool OUTF16, int N, int K>
__global__ __launch_bounds__(256) void k_gemm_f16(const f16* __restrict__ A,
                                                  const f16* __restrict__ Wt,
                                                  const float* __restrict__ bias,
                                                  void* __restrict__ Cv,
                                                  int M,
                                                  const float* __restrict__ win,
                                                  int g0,
                                                  double* __restrict__ p0,
                                                  double* __restrict__ p1)
{
    __shared__ __align__(16) f16 As[128][64];
    __shared__ __align__(16) f16 Bs[128][64];

    const int t  = threadIdx.x;
    const int l  = t & 63;
    const int wv = t >> 6;
    const int wr = wv >> 1, wc = wv & 1;
    const int lm = l & 15, lk = l >> 4;

    // T1: XCD-chunked swizzle (identity when nwg % 8 != 0)
    const int gx = gridDim.x;
    const int nwg = gx * gridDim.y;
    const int orig = blockIdx.y * gx + blockIdx.x;
    int tile = orig;
    if ((nwg & 7) == 0) tile = (orig & 7) * (nwg >> 3) + (orig >> 3);
    const int bm = tile / gx;
    const int bn = tile % gx;

    const f16* Ab = A  + (size_t)bm * 128 * K;
    const f16* Bb = Wt + (size_t)bn * 128 * K;
    char* sA = (char*)&As[0][0];
    char* sB = (char*)&Bs[0][0];

    const int rswz = lm & 7;          // fragment rows: row&7 == lm&7

    f32x4 acc[4][4] = {};

    for (int k0 = 0; k0 < K; k0 += 64) {
        // stage 128x64 tiles: 1024 16B chunks each; 4 rounds x 256 threads.
#pragma unroll
        for (int r = 0; r < 4; ++r) {
            const int c = r * 256 + t;
            const int row = c >> 3;
            const int sl = (c & 7) ^ (row & 7);
            const size_t goff = (size_t)row * K + (size_t)k0 + (size_t)sl * 8;
            gl_lds16(Ab + goff, sA + (size_t)c * 16);
            gl_lds16(Bb + goff, sB + (size_t)c * 16);
        }
        __syncthreads();

#pragma unroll
        for (int ks = 0; ks < 2; ++ks) {
            const int rd = ((ks * 4 + lk) ^ rswz) * 16;
            f16x8 af[4], bf[4];
#pragma unroll
            for (int i = 0; i < 4; ++i) {
                af[i] = *reinterpret_cast<const f16x8*>(sA + (wr * 64 + i * 16 + lm) * 128 + rd);
                bf[i] = *reinterpret_cast<const f16x8*>(sB + (wc * 64 + i * 16 + lm) * 128 + rd);
            }
#pragma unroll
            for (int i = 0; i < 4; ++i)
#pragma unroll
                for (int j = 0; j < 4; ++j)
                    acc[i][j] = __builtin_amdgcn_mfma_f32_16x16x32_f16(af[i], bf[j], acc[i][j], 0, 0, 0);
        }
        __syncthreads();
    }

    // C/D fragment: col = lane&15 (+j*16), row = (lane>>4)*4 + q (+i*16)
    const int col0 = bn * 128 + wc * 64;

    if (MODE == 0) {
        const int row0 = bm * 128 + wr * 64;
#pragma unroll
        for (int j = 0; j < 4; ++j) {
            const int col = col0 + j * 16 + lm;
            const float bv = bias[col];
#pragma unroll
            for (int i = 0; i < 4; ++i)
#pragma unroll
                for (int q = 0; q < 4; ++q) {
                    const int row = row0 + i * 16 + lk * 4 + q;
                    float v = acc[i][j][q] + bv;
                    if (TANH) v = fast_tanh(v);
                    if (OUTF16) ((f16*)Cv)[(size_t)row * N + col] = (f16)v;
                    else        ((float*)Cv)[(size_t)row * N + col] = v;
                }
        }
    } else {  // MODE 2: loss vs window, no store
        __shared__ double sm[256];
        double s0 = 0.0, s1 = 0.0;
#pragma unroll
        for (int i = 0; i < 4; ++i) {
#pragma unroll
            for (int q = 0; q < 4; ++q) {
                const int rl = bm * 128 + wr * 64 + i * 16 + lk * 4 + q;
                const int g  = g0 + rl;
                const int tt = g & 127;
#pragma unroll
                for (int j = 0; j < 4; ++j) {
                    const int col = col0 + j * 16 + lm;
                    const float v = acc[i][j][q] + bias[col];
                    const float d = v - win[(size_t)g * 512 + col];
                    if (tt == 0) s0 += (double)d * d;
                    else         s1 += (double)d * d;
                }
            }
        }
        sm[t] = s0;
        __syncthreads();
        for (int o = 128; o > 0; o >>= 1) {
            if (t < o) sm[t] += sm[t + o];
            __syncthreads();
        }
        if (t == 0) p0[tile] = sm[0];
        __syncthreads();
        sm[t] = s1;
        __syncthreads();
        for (int o = 128; o > 0; o >>= 1) {
            if (t < o) sm[t] += sm[t + o];
            __syncthreads();
        }
        if (t == 0) p1[tile] = sm[0];
    }
}

// ---------------------------------------------------------------------------
__global__ __launch_bounds__(256) void k_wt(const float* __restrict__ W,
                                            f16* __restrict__ Wt, int K, int N)
{
    __shared__ float tl[32][33];
    const int n0 = blockIdx.x * 32, k0 = blockIdx.y * 32;
    const int tx = threadIdx.x & 31, ty = threadIdx.x >> 5;
#pragma unroll
    for (int i = 0; i < 32; i += 8)
        tl[ty + i][tx] = W[(size_t)(k0 + ty + i) * N + n0 + tx];
    __syncthreads();
#pragma unroll
    for (int i = 0; i < 32; i += 8)
        Wt[(size_t)(n0 + ty + i) * K + k0 + tx] = (f16)tl[tx][ty + i];
}

__global__ __launch_bounds__(256) void k_gather_all(const float* __restrict__ win,
                                                    f16* __restrict__ out, int g0, int nrows)
{
    const int i = blockIdx.x * 256 + threadIdx.x;
    if (i >= nrows * 64) return;
    const int r = i >> 6, c8 = i & 63;
    const float* s = win + ((size_t)(g0 + r)) * 512 + c8 * 8;
    const float4 v0 = *reinterpret_cast<const float4*>(s);
    const float4 v1 = *reinterpret_cast<const float4*>(s + 4);
    f16x8 o;
    o[0] = (f16)v0.x; o[1] = (f16)v0.y; o[2] = (f16)v0.z; o[3] = (f16)v0.w;
    o[4] = (f16)v1.x; o[5] = (f16)v1.y; o[6] = (f16)v1.z; o[7] = (f16)v1.w;
    *reinterpret_cast<f16x8*>(out + (size_t)r * 512 + c8 * 8) = o;
}

__global__ __launch_bounds__(256) void k_gather_z0(const float* __restrict__ cZfull,
                                                   float* __restrict__ z0f32,
                                                   f16* __restrict__ z0f16)
{
    const int i = blockIdx.x * 256 + threadIdx.x;     // 512*32 float4s
    if (i >= 512 * 32) return;
    const int b = i >> 5, c4 = i & 31;
    const float4 v = *reinterpret_cast<const float4*>(cZfull + (size_t)b * 16384 + c4 * 4);
    *reinterpret_cast<float4*>(z0f32 + (size_t)b * 128 + c4 * 4) = v;
    f16x4 o;
    o[0] = (f16)v.x; o[1] = (f16)v.y; o[2] = (f16)v.z; o[3] = (f16)v.w;
    *reinterpret_cast<f16x4*>(z0f16 + (size_t)b * 128 + c4 * 4) = o;
}

// ---------------------------------------------------------------------------
// Koopman closed form + linear loss + decin build. 16 threads/row.
// ---------------------------------------------------------------------------
__global__ __launch_bounds__(256) void k_koop(const float* __restrict__ cZ,
                                              const float* __restrict__ z0,
                                              const float* __restrict__ pK,
                                              int g0,
                                              f16* __restrict__ decin,
                                              double* __restrict__ p0)
{
    const int idx = blockIdx.x * 256 + threadIdx.x;
    const int r = idx >> 4, c8 = idx & 15;
    const int g = g0 + r;
    const int tt = g & 127;
    const int bb = g >> 7;

    float zt[8];
    *reinterpret_cast<float4*>(zt)     = *reinterpret_cast<const float4*>(cZ + (size_t)r * 128 + c8 * 8);
    *reinterpret_cast<float4*>(zt + 4) = *reinterpret_cast<const float4*>(cZ + (size_t)r * 128 + c8 * 8 + 4);

    double s = 0.0;
    float ov[8];
    if (tt == 0) {
#pragma unroll
        for (int k = 0; k < 8; ++k) ov[k] = zt[k];
    } else {
        float zz[8], qq[8];
        *reinterpret_cast<float4*>(zz)     = *reinterpret_cast<const float4*>(z0 + (size_t)bb * 128 + c8 * 8);
        *reinterpret_cast<float4*>(zz + 4) = *reinterpret_cast<const float4*>(z0 + (size_t)bb * 128 + c8 * 8 + 4);
        *reinterpret_cast<float4*>(qq)     = *reinterpret_cast<const float4*>(pK + (size_t)bb * 128 + c8 * 8);
        *reinterpret_cast<float4*>(qq + 4) = *reinterpret_cast<const float4*>(pK + (size_t)bb * 128 + c8 * 8 + 4);
        const float tf = KDT * (float)tt;
#pragma unroll
        for (int pr = 0; pr < 4; ++pr) {
            const float e = __expf(qq[2 * pr] * tf);
            float sn, cs;
            __sincosf(qq[2 * pr + 1] * tf, &sn, &cs);
            const float zx = zz[2 * pr], zy = zz[2 * pr + 1];
            const float a = e * (cs * zx - sn * zy);
            const float b = e * (sn * zx + cs * zy);
            ov[2 * pr] = a; ov[2 * pr + 1] = b;
            const float d0 = a - zt[2 * pr], d1 = b - zt[2 * pr + 1];
            s += (double)d0 * d0 + (double)d1 * d1;
        }
    }
    f16x8 o;
#pragma unroll
    for (int k = 0; k < 8; ++k) o[k] = (f16)ov[k];
    *reinterpret_cast<f16x8*>(decin + (size_t)r * 128 + c8 * 8) = o;

    __shared__ double sm[256];
    sm[threadIdx.x] = s;
    __syncthreads();
    for (int off = 128; off > 0; off >>= 1) {
        if (threadIdx.x < (unsigned)off) sm[threadIdx.x] += sm[threadIdx.x + off];
        __syncthreads();
    }
    if (threadIdx.x == 0) p0[blockIdx.x] = sm[0];
}

// ---------------------------------------------------------------------------
__global__ __launch_bounds__(256) void k_finalize(const double* __restrict__ pb,
                                                  float* __restrict__ out)
{
    __shared__ double sm[256];
    const int t = threadIdx.x;
    double a0 = 0.0, a1 = 0.0, a2 = 0.0;
    for (int i = t; i < 4096; i += 256) a0 += pb[PB_LIN + i];
    for (int i = t; i < 2048; i += 256) a1 += pb[PB_REC + i];
    for (int i = t; i < 2048; i += 256) a2 += pb[PB_PRED + i];

    double r[3];
    double v[3] = {a0, a1, a2};
    for (int k = 0; k < 3; ++k) {
        sm[t] = v[k];
        __syncthreads();
        for (int o = 128; o > 0; o >>= 1) {
            if (t < o) sm[t] += sm[t + o];
            __syncthreads();
        }
        r[k] = sm[0];
        __syncthreads();
    }
    if (t == 0) {
        const double linear = r[0] / (65024.0 * 128.0);
        const double recon  = r[1] / (512.0 * 512.0);
        const double pred   = r[2] / (65024.0 * 512.0);
        out[0] = (float)(recon + linear + pred);
        out[1] = (float)recon;
        out[2] = (float)linear;
        out[3] = (float)pred;
    }
}

// ---------------------------------------------------------------------------
extern "C" void kernel_launch(void* const* d_in, const int* in_sizes, int n_in,
                              void* d_out, int out_size, void* d_ws, size_t ws_size,
                              hipStream_t stream)
{
    const float* window = (const float*)d_in[0];
    const float* eW1 = (const float*)d_in[1];
    const float* eb1 = (const float*)d_in[2];
    const float* eW2 = (const float*)d_in[3];
    const float* eb2 = (const float*)d_in[4];
    const float* eW3 = (const float*)d_in[5];
    const float* eb3 = (const float*)d_in[6];
    const float* dW1 = (const float*)d_in[7];
    const float* db1 = (const float*)d_in[8];
    const float* dW2 = (const float*)d_in[9];
    const float* db2 = (const float*)d_in[10];
    const float* dW3 = (const float*)d_in[11];
    const float* db3 = (const float*)d_in[12];
    const float* kW1 = (const float*)d_in[13];
    const float* kb1 = (const float*)d_in[14];
    const float* kW2 = (const float*)d_in[15];
    const float* kb2 = (const float*)d_in[16];
    float* out = (float*)d_out;
    (void)in_sizes; (void)n_in; (void)out_size;

    // unchunked if workspace allows (~380 MB needed); harness gives 512 MiB
    const int nch = (ws_size >= (420ull << 20)) ? 1 : 4;
    const int MC  = 65536 / nch;

    char* p = (char*)d_ws;
    size_t off = 0;
    auto takeB = [&](size_t bytes) -> char* {
        char* r = p + off;
        off += (bytes + 255) & ~(size_t)255;
        return r;
    };
    double* pb = (double*)takeB(PB_TOTAL * 8);
    f16* eW1t = (f16*)takeB((size_t)512 * 1024 * 2);
    f16* eW2t = (f16*)takeB((size_t)1024 * 1024 * 2);
    f16* eW3t = (f16*)takeB((size_t)1024 * 128 * 2);
    f16* dW1t = (f16*)takeB((size_t)128 * 1024 * 2);
    f16* dW2t = (f16*)takeB((size_t)1024 * 1024 * 2);
    f16* dW3t = (f16*)takeB((size_t)1024 * 512 * 2);
    f16* kW1t = (f16*)takeB((size_t)128 * 128 * 2);
    f16* kW2t = (f16*)takeB((size_t)128 * 128 * 2);
    float* z0f32 = (float*)takeB((size_t)65536 * 4);
    f16* z0f16 = (f16*)takeB((size_t)65536 * 2);
    f16* hK = (f16*)takeB((size_t)65536 * 2);
    float* pKbuf = (float*)takeB((size_t)65536 * 4);
    float* cZfull = (float*)takeB((size_t)65536 * 128 * 4);   // 32 MB
    f16* cIn  = (f16*)takeB((size_t)MC * 512 * 2);
    f16* cH1  = (f16*)takeB((size_t)MC * 1024 * 2);
    f16* cH2  = (f16*)takeB((size_t)MC * 1024 * 2);
    f16* decin = (f16*)takeB((size_t)MC * 128 * 2);

    hipMemsetAsync(pb, 0, PB_TOTAL * 8, stream);

    auto WT = [&](const float* W, f16* Wt, int K, int N) {
        k_wt<<<dim3(N / 32, K / 32), 256, 0, stream>>>(W, Wt, K, N);
    };

    // weight prep
    WT(eW1, eW1t, 512, 1024);  WT(eW2, eW2t, 1024, 1024); WT(eW3, eW3t, 1024, 128);
    WT(dW1, dW1t, 128, 1024);  WT(dW2, dW2t, 1024, 1024); WT(dW3, dW3t, 1024, 512);
    WT(kW1, kW1t, 128, 128);   WT(kW2, kW2t, 128, 128);

    // Phase A: encoder over all rows -> cZfull
    for (int c = 0; c < nch; ++c) {
        const int g0 = c * MC;
        k_gather_all<<<MC * 64 / 256, 256, 0, stream>>>(window, cIn, g0, MC);
        k_gemm_f16<0, true, true, 1024, 512><<<dim3(8, MC / 128), 256, 0, stream>>>(
            cIn, eW1t, eb1, cH1, MC, nullptr, 0, nullptr, nullptr);
        k_gemm_f16<0, true, true, 1024, 1024><<<dim3(8, MC / 128), 256, 0, stream>>>(
            cH1, eW2t, eb2, cH2, MC, nullptr, 0, nullptr, nullptr);
        k_gemm_f16<0, false, false, 128, 1024><<<dim3(1, MC / 128), 256, 0, stream>>>(
            cH2, eW3t, eb3, cZfull + (size_t)g0 * 128, MC, nullptr, 0, nullptr, nullptr);
    }

    // Phase B: z0 + koopman params
    k_gather_z0<<<64, 256, 0, stream>>>(cZfull, z0f32, z0f16);
    k_gemm_f16<0, true, true, 128, 128><<<dim3(1, 4), 256, 0, stream>>>(
        z0f16, kW1t, kb1, hK, 512, nullptr, 0, nullptr, nullptr);
    k_gemm_f16<0, false, false, 128, 128><<<dim3(1, 4), 256, 0, stream>>>(
        hK, kW2t, kb2, pKbuf, 512, nullptr, 0, nullptr, nullptr);

    // Phase C: koopman rollout + decoder + losses
    for (int c = 0; c < nch; ++c) {
        const int g0 = c * MC;
        k_koop<<<MC / 16, 256, 0, stream>>>(cZfull + (size_t)g0 * 128, z0f32, pKbuf,
                                            g0, decin, pb + PB_LIN + (g0 >> 4));
        k_gemm_f16<0, true, true, 1024, 128><<<dim3(8, MC / 128), 256, 0, stream>>>(
            decin, dW1t, db1, cH1, MC, nullptr, 0, nullptr, nullptr);
        k_gemm_f16<0, true, true, 1024, 1024><<<dim3(8, MC / 128), 256, 0, stream>>>(
            cH1, dW2t, db2, cH2, MC, nullptr, 0, nullptr, nullptr);
        k_gemm_f16<2, false, false, 512, 1024><<<dim3(4, MC / 128), 256, 0, stream>>>(
            cH2, dW3t, db3, nullptr, MC,
            window, g0, pb + PB_REC + (g0 >> 5), pb + PB_PRED + (g0 >> 5));
    }

    k_finalize<<<1, 256, 0, stream>>>(pb, out);
}